// Round 5
// baseline (630.033 us; speedup 1.0000x reference)
//
#include <hip/hip_runtime.h>

#define NN 10000
#define NPAD 10112
#define EE 160000
#define DD 128
#define KT 4

constexpr int JSPLIT = 16;
constexpr int BM = 128;                     // i-tile per block
constexpr int ITILES = 79;                  // ceil(10000/128); 79*128 = 10112 = NPAD
constexpr int JCHUNK = 628;                 // multiple of 4 -> 16B-aligned q float4 loads
constexpr double FPSCALE = 1099511627776.0; // 2^40
constexpr float NEG_INF = -3.402823466e38f;
constexpr float NLN2 = -0.69314718055994531f;
constexpr float GMAX = 16.75f;  // g = -ln(-ln(q+1e-8)) <= -ln(2^-24) ~= 16.64 for q<1 (f32)

typedef __attribute__((ext_vector_type(8))) short short8;
typedef __attribute__((ext_vector_type(8))) unsigned short ushort8;
typedef __attribute__((ext_vector_type(4))) float f32x4;

// -------------------- bf16 split helpers --------------------
__device__ inline unsigned short bf_rn(float x) {
    unsigned u = __float_as_uint(x);
    unsigned r = (u + 0x7fffu + ((u >> 16) & 1u)) >> 16;
    return (unsigned short)r;
}
__device__ inline float bf_f(unsigned short h) {
    return __uint_as_float(((unsigned)h) << 16);
}

// -------------------- fast accurate ln (relative accuracy kept near x=1) ----------
// Direct atanh-series path on (0.6875, 1.375) avoids the catastrophic relative
// error hardware v_log_f32 has for ln(1+eps). REQUIRED for the inner gumbel log.
__device__ inline float fast_ln(float x) {
    int bits = __float_as_int(x);
    int e = ((bits >> 23) & 0xff) - 127;
    float m = __int_as_float((bits & 0x007fffff) | 0x3f800000); // [1,2)
    bool direct = (x > 0.6875f) && (x < 1.375f);
    float xm = direct ? x : m;
    float ef = direct ? 0.f : (float)e;
    float t = (xm - 1.f) * __builtin_amdgcn_rcpf(xm + 1.f);
    float t2 = t * t;
    float p = 0.09090909f;               // 1/11
    p = fmaf(p, t2, 0.11111111f);        // 1/9
    p = fmaf(p, t2, 0.14285714f);        // 1/7
    p = fmaf(p, t2, 0.2f);               // 1/5
    p = fmaf(p, t2, 0.33333333f);        // 1/3
    p = fmaf(p, t2, 1.f);
    p = 2.f * t * p;
    return fmaf(ef, 0.69314718055994531f, p);
}

// -------------------- h0 = x @ W --------------------
__global__ void k_gemm(const float* __restrict__ x, const float* __restrict__ W,
                       float* __restrict__ hpre) {
    int row = blockIdx.x;
    int c = threadIdx.x;   // 128
    __shared__ float xs[DD];
    xs[c] = x[row * DD + c];
    __syncthreads();
    float acc = 0.f;
#pragma unroll 8
    for (int k = 0; k < DD; ++k) acc += xs[k] * W[k * DD + c];
    hpre[row * DD + c] = acc;
}

// -------------------- CSR build: count -> scan(+dinv) -> fill --------------------
__global__ void k_count(const int* __restrict__ ei, int* __restrict__ cnt) {
    int e = blockIdx.x * blockDim.x + threadIdx.x;
    if (e < EE) atomicAdd(&cnt[ei[e]], 1);
}

__global__ void k_scan(int* __restrict__ cnt, int* __restrict__ rowptr,
                       float* __restrict__ dinv) {
    __shared__ int part[1024];
    int t = threadIdx.x;
    int base = t * 10;
    int loc[10];
    int s = 0;
#pragma unroll
    for (int k = 0; k < 10; ++k) {
        int idx = base + k;
        int v = (idx < NN) ? cnt[idx] : 0;
        loc[k] = s; s += v;
    }
    part[t] = s;
    __syncthreads();
    for (int off = 1; off < 1024; off <<= 1) {
        int v = (t >= off) ? part[t - off] : 0;
        __syncthreads();
        part[t] += v;
        __syncthreads();
    }
    int pre = (t > 0) ? part[t - 1] : 0;
#pragma unroll
    for (int k = 0; k < 10; ++k) {
        int idx = base + k;
        if (idx < NN) {
            rowptr[idx] = pre + loc[k];
            int d = cnt[idx];
            dinv[idx] = 1.0f / sqrtf((float)(d + 1));  // + self loop
            cnt[idx] = 0;  // reset for fill phase
        }
    }
    if (t == 1023) rowptr[NN] = part[1023];
}

__global__ void k_fill(const int* __restrict__ ei, const int* __restrict__ rowptr,
                       int* __restrict__ wcnt, int* __restrict__ csr) {
    int e = blockIdx.x * blockDim.x + threadIdx.x;
    if (e >= EE) return;
    int r = ei[e];
    int pos = atomicAdd(&wcnt[r], 1);
    csr[rowptr[r] + pos] = ei[EE + e];
}

// -------------------- deterministic gather: h = sym-norm agg + b -----------------
__global__ void k_gather(const float* __restrict__ hpre, const int* __restrict__ rowptr,
                         const int* __restrict__ csr, const float* __restrict__ dinv,
                         const float* __restrict__ b, float* __restrict__ out) {
    int r = blockIdx.x;
    int t = threadIdx.x;  // 128
    float dr = dinv[r];
    float v0 = hpre[r * DD + t] * dr * dr;
    long long acc = llrint((double)v0 * FPSCALE);
    int s = rowptr[r], e = rowptr[r + 1];
    for (int k = s; k < e; ++k) {
        int c = csr[k];
        float w = dr * dinv[c];
        float p = hpre[c * DD + t] * w;
        acc += llrint((double)p * FPSCALE);
    }
    out[r * DD + t] = (float)((double)acc * (1.0 / FPSCALE)) + b[t];
}

// -------------------- bf16 hi/lo split + row norms (padded rows) --------------------
__global__ void k_prep(const float* __restrict__ h, unsigned short* __restrict__ hhi,
                       unsigned short* __restrict__ hlo, float* __restrict__ sqout) {
    int row = blockIdx.x;      // NPAD
    int c = threadIdx.x;       // 64
    float v0 = 0.f, v1 = 0.f;
    if (row < NN) { v0 = h[row * DD + c]; v1 = h[row * DD + 64 + c]; }
    unsigned short h0 = bf_rn(v0), h1 = bf_rn(v1);
    float r0 = v0 - bf_f(h0), r1 = v1 - bf_f(h1);
    unsigned short l0 = bf_rn(r0), l1 = bf_rn(r1);
    hhi[row * DD + c] = h0; hhi[row * DD + 64 + c] = h1;
    hlo[row * DD + c] = l0; hlo[row * DD + 64 + c] = l1;
    float s = v0 * v0 + v1 * v1;
#pragma unroll
    for (int off = 32; off; off >>= 1) s += __shfl_xor(s, off, 64);
    if (c == 0) sqout[row] = s;
}

#define BETTER(v1, j1, v2, j2) ((v1) > (v2) || ((v1) == (v2) && (j1) < (j2)))

#define INSERT4(tvv, tjj, v, j)                                               \
    if (BETTER(v, j, tvv[3], tjj[3])) {                                       \
        tvv[3] = v; tjj[3] = j;                                               \
        _Pragma("unroll")                                                     \
        for (int rr = 3; rr > 0; --rr) {                                      \
            if (BETTER(tvv[rr], tjj[rr], tvv[rr - 1], tjj[rr - 1])) {         \
                float t0 = tvv[rr]; tvv[rr] = tvv[rr - 1]; tvv[rr - 1] = t0;  \
                int t1 = tjj[rr]; tjj[rr] = tjj[rr - 1]; tjj[rr - 1] = t1;    \
            }                                                                 \
        }                                                                     \
    }

// -------------------- MFMA pairwise-dist + gumbel-filtered top-4 --------------------
// BM=128: each of 4 waves owns 2 i-strips (w and w+4). j-tile (64x128 hi+lo) in LDS,
// 16B-chunk XOR swizzle. D = mfma(A=j, B=i): col = i (lane&15), row = j (kl*4+r).
// Filter: v <= GMAX - T*d2; skip q load + logs when that bound can't beat tv[3].
__global__ __launch_bounds__(256, 3) void k_topk(
    const unsigned short* __restrict__ hhi, const unsigned short* __restrict__ hlo,
    const float* __restrict__ sq, const float* __restrict__ q,
    const float* __restrict__ tptr, float* __restrict__ pvals, int* __restrict__ pidx) {
    __shared__ __align__(16) unsigned short Bhi[64 * DD];  // 16 KB (j-tile hi)
    __shared__ __align__(16) unsigned short Blo[64 * DD];  // 16 KB (j-tile lo)
    __shared__ float sqs[64];

    const int blk = blockIdx.x;
    const int itile = blk >> 4;
    const int split = blk & 15;
    const int ibase = itile * BM;
    const int jstart = split * JCHUNK;
    const int jlimit = min(NN, jstart + JCHUNK);
    const float T = *tptr;

    const int tid = threadIdx.x;
    const int w = tid >> 6;
    const int lane = tid & 63;
    const int n = lane & 15;     // i-col within strip / A(j) row
    const int kl = lane >> 4;    // k-slice group; D row group

    // ---- i-side register fragments for 2 strips (B operand) ----
    short8 ihi0[4], ilo0[4], ihi1[4], ilo1[4];
    {
        int ra0 = ibase + 16 * w + n;            // strip 0
        int ra1 = ibase + 16 * (w + 4) + n;      // strip 1  (<= 10111 < NPAD)
        const unsigned short* pa0 = hhi + ra0 * DD + kl * 8;
        const unsigned short* pl0 = hlo + ra0 * DD + kl * 8;
        const unsigned short* pa1 = hhi + ra1 * DD + kl * 8;
        const unsigned short* pl1 = hlo + ra1 * DD + kl * 8;
#pragma unroll
        for (int ks = 0; ks < 4; ++ks) {
            ihi0[ks] = *reinterpret_cast<const short8*>(pa0 + ks * 32);
            ilo0[ks] = *reinterpret_cast<const short8*>(pl0 + ks * 32);
            ihi1[ks] = *reinterpret_cast<const short8*>(pa1 + ks * 32);
            ilo1[ks] = *reinterpret_cast<const short8*>(pl1 + ks * 32);
        }
    }

    float sqi[2];
    const float* qrow[2];
#pragma unroll
    for (int s = 0; s < 2; ++s) {
        int i = ibase + 16 * (w + 4 * s) + n;
        int ic = min(i, NN - 1);
        sqi[s] = sq[ic];
        qrow[s] = q + (size_t)ic * NN;
    }

    float tv0[4], tv1[4];
    int tj0[4], tj1[4];
#pragma unroll
    for (int s = 0; s < 4; ++s) {
        tv0[s] = NEG_INF; tj0[s] = 0x7fffffff;
        tv1[s] = NEG_INF; tj1[s] = 0x7fffffff;
    }

    for (int jt = 0; jt < 10; ++jt) {
        const int jbase = jstart + jt * 64;
        __syncthreads();  // previous-tile LDS reads done
        // ---- stage j-tile (hi+lo) with 16B-chunk XOR swizzle; stage sq slice ----
#pragma unroll
        for (int p = 0; p < 4; ++p) {
            int c = p * 256 + tid;
            int row = c >> 4, cl = c & 15;
            int cp = cl ^ (row & 7);
            int gsrc = (jbase + row) * DD + cl * 8;   // row <= 10059 < NPAD
            ushort8 vh = *reinterpret_cast<const ushort8*>(hhi + gsrc);
            ushort8 vl = *reinterpret_cast<const ushort8*>(hlo + gsrc);
            *reinterpret_cast<ushort8*>(&Bhi[row * DD + cp * 8]) = vh;
            *reinterpret_cast<ushort8*>(&Blo[row * DD + cp * 8]) = vl;
        }
        if (tid < 64) sqs[tid] = sq[jbase + tid];
        __syncthreads();

#pragma unroll
        for (int jf = 0; jf < 4; ++jf) {
            const int arow = 16 * jf + n;
            const int xr = n & 7;
            short8 jh[4], jl[4];
#pragma unroll
            for (int ks = 0; ks < 4; ++ks) {
                int cp = (ks * 4 + kl) ^ xr;
                jh[ks] = *reinterpret_cast<const short8*>(&Bhi[arow * DD + cp * 8]);
                jl[ks] = *reinterpret_cast<const short8*>(&Blo[arow * DD + cp * 8]);
            }
            f32x4 acc0 = {0.f, 0.f, 0.f, 0.f};
            f32x4 acc1 = {0.f, 0.f, 0.f, 0.f};
#pragma unroll
            for (int ks = 0; ks < 4; ++ks) {
                acc0 = __builtin_amdgcn_mfma_f32_16x16x32_bf16(jh[ks], ihi0[ks], acc0, 0, 0, 0);
                acc1 = __builtin_amdgcn_mfma_f32_16x16x32_bf16(jh[ks], ihi1[ks], acc1, 0, 0, 0);
            }
#pragma unroll
            for (int ks = 0; ks < 4; ++ks) {
                acc0 = __builtin_amdgcn_mfma_f32_16x16x32_bf16(jl[ks], ihi0[ks], acc0, 0, 0, 0);
                acc1 = __builtin_amdgcn_mfma_f32_16x16x32_bf16(jl[ks], ihi1[ks], acc1, 0, 0, 0);
            }
#pragma unroll
            for (int ks = 0; ks < 4; ++ks) {
                acc0 = __builtin_amdgcn_mfma_f32_16x16x32_bf16(jh[ks], ilo0[ks], acc0, 0, 0, 0);
                acc1 = __builtin_amdgcn_mfma_f32_16x16x32_bf16(jh[ks], ilo1[ks], acc1, 0, 0, 0);
            }

            // ---- epilogue: bound-filtered gumbel + insert, 2 strips x 4 j ----
            const float4 sq4 = *reinterpret_cast<const float4*>(&sqs[16 * jf + kl * 4]);
            const int j0 = jbase + 16 * jf + kl * 4;
            const float* sqp = reinterpret_cast<const float*>(&sq4);
#pragma unroll
            for (int r = 0; r < 4; ++r) {
                int j = j0 + r;
                {   // strip 0
                    float d2 = fmaxf(fmaf(-2.f, acc0[r], sqi[0] + sqp[r]), 0.f);
                    float vb = fmaf(-T, d2, GMAX);
                    if (vb >= tv0[3] && j < jlimit) {
                        float u = -fast_ln(qrow[0][j] + 1e-8f);
                        float g = __log2f(u) * NLN2;
                        float v = fmaf(-T, d2, g);
                        INSERT4(tv0, tj0, v, j)
                    }
                }
                {   // strip 1
                    float d2 = fmaxf(fmaf(-2.f, acc1[r], sqi[1] + sqp[r]), 0.f);
                    float vb = fmaf(-T, d2, GMAX);
                    if (vb >= tv1[3] && j < jlimit) {
                        float u = -fast_ln(qrow[1][j] + 1e-8f);
                        float g = __log2f(u) * NLN2;
                        float v = fmaf(-T, d2, g);
                        INSERT4(tv1, tj1, v, j)
                    }
                }
            }
        }
    }

    // ---- in-block merge: 4 kl-lanes per i-row, 128 rows ----
    __syncthreads();
    float* mv = reinterpret_cast<float*>(Bhi);  // 128 rows x 16 entries (8 KB)
    int* mj = reinterpret_cast<int*>(Blo);
    {
        int rl0 = 16 * w + n;
        int rl1 = 16 * (w + 4) + n;
#pragma unroll
        for (int s = 0; s < 4; ++s) {
            mv[rl0 * 16 + kl * 4 + s] = tv0[s];
            mj[rl0 * 16 + kl * 4 + s] = tj0[s];
            mv[rl1 * 16 + kl * 4 + s] = tv1[s];
            mj[rl1 * 16 + kl * 4 + s] = tj1[s];
        }
    }
    __syncthreads();
    if (tid < BM) {
        int i = ibase + tid;
        float bv[4] = {NEG_INF, NEG_INF, NEG_INF, NEG_INF};
        int bj[4] = {0x7fffffff, 0x7fffffff, 0x7fffffff, 0x7fffffff};
        for (int c = 0; c < 16; ++c) {
            float v = mv[tid * 16 + c];
            int j = mj[tid * 16 + c];
            INSERT4(bv, bj, v, j)
        }
        if (i < NN) {
#pragma unroll
            for (int s = 0; s < 4; ++s) {
                pvals[(split * NN + i) * 4 + s] = bv[s];
                pidx[(split * NN + i) * 4 + s] = bj[s];
            }
        }
    }
}

// -------------------- final cross-split merge + output assembly --------------------
__global__ void k_merge(const float* __restrict__ pvals, const int* __restrict__ pidx,
                        float* __restrict__ out) {
    int i = blockIdx.x * blockDim.x + threadIdx.x;
    if (i >= NN) return;
    float mv[4] = {NEG_INF, NEG_INF, NEG_INF, NEG_INF};
    int mj[4] = {0x7fffffff, 0x7fffffff, 0x7fffffff, 0x7fffffff};
    for (int s = 0; s < JSPLIT; ++s) {
#pragma unroll
        for (int r = 0; r < 4; ++r) {
            float v = pvals[(s * NN + i) * 4 + r];
            int j = pidx[(s * NN + i) * 4 + r];
            INSERT4(mv, mj, v, j)
        }
    }
    float* eidx = out + NN * DD;
    float* erow = eidx + (NN * KT + NN);
    float* lp = erow + (NN * KT + NN);
#pragma unroll
    for (int r = 0; r < 4; ++r) {
        eidx[i * 4 + r] = (float)mj[r];
        erow[i * 4 + r] = (float)i;
        lp[i * 4 + r] = mv[r];
    }
    eidx[NN * KT + i] = (float)i;
    erow[NN * KT + i] = (float)i;
}

extern "C" void kernel_launch(void* const* d_in, const int* in_sizes, int n_in,
                              void* d_out, int out_size, void* d_ws, size_t ws_size,
                              hipStream_t stream) {
    const float* x = (const float*)d_in[0];
    const int* ei = (const int*)d_in[1];
    const float* q = (const float*)d_in[2];
    const float* W = (const float*)d_in[3];
    const float* b = (const float*)d_in[4];
    const float* temp = (const float*)d_in[5];
    float* out = (float*)d_out;

    char* ws = (char*)d_ws;
    float* hpre = (float*)(ws + 0);                         // [0, 5,120,000) dies at k_gather
    unsigned short* hhi = (unsigned short*)(ws + 0);        // 2,588,672 (overlays hpre)
    unsigned short* hlo = (unsigned short*)(ws + 2588672);  // -> 5,177,344
    float* pvals = (float*)(ws + 5177344);                  // 2,560,000 -> 7,737,344
    int* pidx = (int*)(ws + 7737344);                       // 2,560,000 -> 10,297,344
    float* sq = (float*)(ws + 10297344);                    // 40,448 -> 10,337,792
    int* cnt = (int*)(ws + 10337792);                       // 40,000 -> 10,377,792 (also wcnt)
    int* rowptr = (int*)(ws + 10377792);                    // 40,016 -> 10,417,808
    float* dinv = (float*)(ws + 10417808);                  // 40,000 -> 10,457,808
    int* csr = (int*)(ws + 10457808);                       // 640,000 -> 11,097,808

    // zero edge-count histogram each launch (ws poisoned once, never restored)
    hipMemsetAsync(cnt, 0, 40000, stream);

    k_gemm<<<NN, 128, 0, stream>>>(x, W, hpre);
    k_count<<<(EE + 255) / 256, 256, 0, stream>>>(ei, cnt);
    k_scan<<<1, 1024, 0, stream>>>(cnt, rowptr, dinv);
    k_fill<<<(EE + 255) / 256, 256, 0, stream>>>(ei, rowptr, cnt, csr);
    k_gather<<<NN, 128, 0, stream>>>(hpre, rowptr, csr, dinv, b, out);
    k_prep<<<NPAD, 64, 0, stream>>>(out, hhi, hlo, sq);
    k_topk<<<ITILES * JSPLIT, 256, 0, stream>>>(hhi, hlo, sq, q, temp, pvals, pidx);
    k_merge<<<(NN + 255) / 256, 256, 0, stream>>>(pvals, pidx, out);
}

// Round 6
// 563.558 us; speedup vs baseline: 1.1180x; 1.1180x over previous
//
#include <hip/hip_runtime.h>

#define NN 10000
#define NPAD 10112
#define EE 160000
#define DD 128
#define KT 4

constexpr int JSPLIT = 16;
constexpr int ITILES = 157;                 // ceil(10000/64), BM=64
constexpr int JCHUNK = 628;                 // multiple of 4 -> 16B-aligned q float4 loads
constexpr double FPSCALE = 1099511627776.0; // 2^40
constexpr float NEG_INF = -3.402823466e38f;
constexpr float NLN2 = -0.69314718055994531f;

typedef __attribute__((ext_vector_type(8))) short short8;
typedef __attribute__((ext_vector_type(8))) unsigned short ushort8;
typedef __attribute__((ext_vector_type(4))) float f32x4;

// -------------------- bf16 split helpers --------------------
__device__ inline unsigned short bf_rn(float x) {
    unsigned u = __float_as_uint(x);
    unsigned r = (u + 0x7fffu + ((u >> 16) & 1u)) >> 16;
    return (unsigned short)r;
}
__device__ inline float bf_f(unsigned short h) {
    return __uint_as_float(((unsigned)h) << 16);
}

// -------------------- fast accurate ln (relative accuracy kept near x=1) ----------
// Direct atanh-series path on (0.6875, 1.375) keeps relative accuracy through the
// cancellation zone (hardware v_log has ~2^-23 ABSOLUTE error -> useless for ln(1+eps);
// that bug cost round 3). 5 poly terms: worst rel err ~1.6e-6 (split path t<=1/3).
__device__ inline float fast_ln(float x) {
    int bits = __float_as_int(x);
    int e = ((bits >> 23) & 0xff) - 127;
    float m = __int_as_float((bits & 0x007fffff) | 0x3f800000); // [1,2)
    bool direct = (x > 0.6875f) && (x < 1.375f);
    float xm = direct ? x : m;
    float ef = direct ? 0.f : (float)e;
    float t = (xm - 1.f) * __builtin_amdgcn_rcpf(xm + 1.f);
    float t2 = t * t;
    float p = 0.11111111f;               // 1/9
    p = fmaf(p, t2, 0.14285714f);        // 1/7
    p = fmaf(p, t2, 0.2f);               // 1/5
    p = fmaf(p, t2, 0.33333333f);        // 1/3
    p = fmaf(p, t2, 1.f);
    p = 2.f * t * p;
    return fmaf(ef, 0.69314718055994531f, p);
}

// -------------------- h0 = x @ W, LDS-tiled (32 rows/block) --------------------
// W staged once per block: L2 W-traffic 640 MB -> 20 MB. FP add order identical to
// the old per-row kernel (k ascending, sequential fma) -> bit-identical hpre.
__global__ __launch_bounds__(256) void k_gemm(const float* __restrict__ x,
                                              const float* __restrict__ W,
                                              float* __restrict__ hpre) {
    __shared__ float4 Ws4[128 * 32];   // [k][c4]  64 KB
    __shared__ float4 xs4[32 * 32];    // [row][k4] 16 KB
    const int t = threadIdx.x;
    const int r0 = blockIdx.x * 32;
    const float4* W4 = reinterpret_cast<const float4*>(W);
    const float4* x4 = reinterpret_cast<const float4*>(x);
#pragma unroll
    for (int i = 0; i < 16; ++i) Ws4[i * 256 + t] = W4[i * 256 + t];
#pragma unroll
    for (int i = 0; i < 4; ++i) {
        int f = i * 256 + t;
        int g = r0 * 32 + f;
        xs4[f] = (g < NN * 32) ? x4[g] : make_float4(0.f, 0.f, 0.f, 0.f);
    }
    __syncthreads();
    const int c = t & 31;    // float4 column
    const int rg = t >> 5;   // 0..7 -> rows rg*4..rg*4+3
    float4 acc[4] = {};
    for (int k4 = 0; k4 < 32; ++k4) {
        float4 w0 = Ws4[(k4 * 4 + 0) * 32 + c];
        float4 w1 = Ws4[(k4 * 4 + 1) * 32 + c];
        float4 w2 = Ws4[(k4 * 4 + 2) * 32 + c];
        float4 w3 = Ws4[(k4 * 4 + 3) * 32 + c];
#pragma unroll
        for (int r = 0; r < 4; ++r) {
            float4 xv = xs4[(rg * 4 + r) * 32 + k4];
            acc[r].x = fmaf(xv.w, w3.x, fmaf(xv.z, w2.x, fmaf(xv.y, w1.x, fmaf(xv.x, w0.x, acc[r].x))));
            acc[r].y = fmaf(xv.w, w3.y, fmaf(xv.z, w2.y, fmaf(xv.y, w1.y, fmaf(xv.x, w0.y, acc[r].y))));
            acc[r].z = fmaf(xv.w, w3.z, fmaf(xv.z, w2.z, fmaf(xv.y, w1.z, fmaf(xv.x, w0.z, acc[r].z))));
            acc[r].w = fmaf(xv.w, w3.w, fmaf(xv.z, w2.w, fmaf(xv.y, w1.w, fmaf(xv.x, w0.w, acc[r].w))));
        }
    }
#pragma unroll
    for (int r = 0; r < 4; ++r) {
        int row = r0 + rg * 4 + r;
        if (row < NN) reinterpret_cast<float4*>(hpre)[row * 32 + c] = acc[r];
    }
}

// -------------------- CSR build: count -> scan(+dinv) -> fill --------------------
__global__ void k_count(const int* __restrict__ ei, int* __restrict__ cnt) {
    int e = blockIdx.x * blockDim.x + threadIdx.x;
    if (e < EE) atomicAdd(&cnt[ei[e]], 1);
}

__global__ void k_scan(int* __restrict__ cnt, int* __restrict__ rowptr,
                       float* __restrict__ dinv) {
    __shared__ int part[1024];
    int t = threadIdx.x;
    int base = t * 10;
    int loc[10];
    int s = 0;
#pragma unroll
    for (int k = 0; k < 10; ++k) {
        int idx = base + k;
        int v = (idx < NN) ? cnt[idx] : 0;
        loc[k] = s; s += v;
    }
    part[t] = s;
    __syncthreads();
    for (int off = 1; off < 1024; off <<= 1) {
        int v = (t >= off) ? part[t - off] : 0;
        __syncthreads();
        part[t] += v;
        __syncthreads();
    }
    int pre = (t > 0) ? part[t - 1] : 0;
#pragma unroll
    for (int k = 0; k < 10; ++k) {
        int idx = base + k;
        if (idx < NN) {
            rowptr[idx] = pre + loc[k];
            int d = cnt[idx];
            dinv[idx] = 1.0f / sqrtf((float)(d + 1));  // + self loop
            cnt[idx] = 0;  // reset for fill phase
        }
    }
    if (t == 1023) rowptr[NN] = part[1023];
}

__global__ void k_fill(const int* __restrict__ ei, const int* __restrict__ rowptr,
                       int* __restrict__ wcnt, int* __restrict__ csr) {
    int e = blockIdx.x * blockDim.x + threadIdx.x;
    if (e >= EE) return;
    int r = ei[e];
    int pos = atomicAdd(&wcnt[r], 1);
    csr[rowptr[r] + pos] = ei[EE + e];
}

// ---------- deterministic gather + fused bf16-split/row-norm (was k_prep) ----------
// i64 fixed-point accumulation is order-independent -> deterministic; bit-identical
// h to rounds 2-5. Pad rows [NN, NPAD) write zeros to hhi/hlo/sq.
__global__ void k_gather(const float* __restrict__ hpre, const int* __restrict__ rowptr,
                         const int* __restrict__ csr, const float* __restrict__ dinv,
                         const float* __restrict__ b, float* __restrict__ out,
                         unsigned short* __restrict__ hhi, unsigned short* __restrict__ hlo,
                         float* __restrict__ sqout) {
    int r = blockIdx.x;   // NPAD
    int t = threadIdx.x;  // 128
    __shared__ float part[2];
    float outv = 0.f;
    if (r < NN) {
        float dr = dinv[r];
        float v0 = hpre[r * DD + t] * dr * dr;
        long long acc = llrint((double)v0 * FPSCALE);
        int s = rowptr[r], e = rowptr[r + 1];
        for (int k = s; k < e; ++k) {
            int c = csr[k];
            float w = dr * dinv[c];
            float p = hpre[c * DD + t] * w;
            acc += llrint((double)p * FPSCALE);
        }
        outv = (float)((double)acc * (1.0 / FPSCALE)) + b[t];
        out[r * DD + t] = outv;
    }
    unsigned short h0 = bf_rn(outv);
    float rs = outv - bf_f(h0);
    unsigned short l0 = bf_rn(rs);
    hhi[r * DD + t] = h0;
    hlo[r * DD + t] = l0;
    float s2 = outv * outv;
#pragma unroll
    for (int off = 32; off; off >>= 1) s2 += __shfl_xor(s2, off, 64);
    if ((t & 63) == 0) part[t >> 6] = s2;
    __syncthreads();
    if (t == 0) sqout[r] = part[0] + part[1];
}

#define BETTER(v1, j1, v2, j2) ((v1) > (v2) || ((v1) == (v2) && (j1) < (j2)))

#define INSERT4(tvv, tjj, v, j)                                               \
    if (BETTER(v, j, tvv[3], tjj[3])) {                                       \
        tvv[3] = v; tjj[3] = j;                                               \
        _Pragma("unroll")                                                     \
        for (int rr = 3; rr > 0; --rr) {                                      \
            if (BETTER(tvv[rr], tjj[rr], tvv[rr - 1], tjj[rr - 1])) {         \
                float t0 = tvv[rr]; tvv[rr] = tvv[rr - 1]; tvv[rr - 1] = t0;  \
                int t1 = tjj[rr]; tjj[rr] = tjj[rr - 1]; tjj[rr - 1] = t1;    \
            }                                                                 \
        }                                                                     \
    }

// -------------------- MFMA pairwise-dist + gumbel + top-4 (BM=64) --------------------
// Operand-swapped: D = mfma(A=j-rows(LDS), B=i-rows(regs)): D col = i (lane&15),
// D row = j (kl*4+r, 4 consecutive per lane) -> q is one float4 per lane per jf.
// LDS exactly 32 KB (no sqs buffer; sq read from global, L2-hot) -> 5 blocks/CU.
// Outer gate is strict v > tv[3]: per-lane j strictly increases, so the lexicographic
// tie-break can never fire on the gate (later j loses ties) — identical selection.
__global__ __launch_bounds__(256, 5) void k_topk(
    const unsigned short* __restrict__ hhi, const unsigned short* __restrict__ hlo,
    const float* __restrict__ sq, const float* __restrict__ q,
    const float* __restrict__ tptr, float* __restrict__ pvals, int* __restrict__ pidx) {
    __shared__ __align__(16) unsigned short Bhi[64 * DD];  // 16 KB (j-tile hi)
    __shared__ __align__(16) unsigned short Blo[64 * DD];  // 16 KB (j-tile lo)

    const int blk = blockIdx.x;
    const int itile = blk >> 4;
    const int split = blk & 15;
    const int ibase = itile * 64;
    const int jstart = split * JCHUNK;
    const int jlimit = min(NN, jstart + JCHUNK);
    const float T = *tptr;

    const int tid = threadIdx.x;
    const int w = tid >> 6;
    const int lane = tid & 63;
    const int n = lane & 15;     // i-col within wave strip / B col
    const int kl = lane >> 4;    // k-slice group; D row group

    // ---- i-side register fragments (B operand): row ibase+16w+n ----
    short8 ihi[4], ilo[4];
    {
        int ra = ibase + 16 * w + n;        // <= 10047 < NPAD
        const unsigned short* pa = hhi + ra * DD + kl * 8;
        const unsigned short* pl = hlo + ra * DD + kl * 8;
#pragma unroll
        for (int ks = 0; ks < 4; ++ks) {
            ihi[ks] = *reinterpret_cast<const short8*>(pa + ks * 32);
            ilo[ks] = *reinterpret_cast<const short8*>(pl + ks * 32);
        }
    }

    const int i_glob = ibase + 16 * w + n;
    const int ic = min(i_glob, NN - 1);
    const float sqi = sq[ic];
    const float* qrow = q + (size_t)ic * NN;

    float tv[4];
    int tj[4];
#pragma unroll
    for (int s = 0; s < 4; ++s) { tv[s] = NEG_INF; tj[s] = 0x7fffffff; }

    for (int jt = 0; jt < 10; ++jt) {
        const int jbase = jstart + jt * 64;
        __syncthreads();  // previous-tile LDS reads done
        // ---- stage j-tile (hi+lo) with 16B-chunk XOR swizzle ----
#pragma unroll
        for (int p = 0; p < 4; ++p) {
            int c = p * 256 + tid;
            int row = c >> 4, cl = c & 15;
            int cp = cl ^ (row & 7);
            int gsrc = (jbase + row) * DD + cl * 8;   // row <= 10059 < NPAD
            ushort8 vh = *reinterpret_cast<const ushort8*>(hhi + gsrc);
            ushort8 vl = *reinterpret_cast<const ushort8*>(hlo + gsrc);
            *reinterpret_cast<ushort8*>(&Bhi[row * DD + cp * 8]) = vh;
            *reinterpret_cast<ushort8*>(&Blo[row * DD + cp * 8]) = vl;
        }
        __syncthreads();

        // ---- q prefetch: one float4 per jf (j = jbase + 16jf + kl*4 + 0..3) ----
        float4 qv[4];
        const int j0base = jbase + kl * 4;
#pragma unroll
        for (int jf = 0; jf < 4; ++jf) {
            int j0 = j0base + 16 * jf;
            int jq = min(j0, NN - 4);       // clamp padded tail (masked later); 16B aligned
            qv[jf] = *reinterpret_cast<const float4*>(qrow + jq);
        }

#pragma unroll
        for (int jf = 0; jf < 4; ++jf) {
            const int arow = 16 * jf + n;
            const int xr = n & 7;
            short8 jh[4], jl[4];
#pragma unroll
            for (int ks = 0; ks < 4; ++ks) {
                int cp = (ks * 4 + kl) ^ xr;
                jh[ks] = *reinterpret_cast<const short8*>(&Bhi[arow * DD + cp * 8]);
                jl[ks] = *reinterpret_cast<const short8*>(&Blo[arow * DD + cp * 8]);
            }
            f32x4 acc = {0.f, 0.f, 0.f, 0.f};
#pragma unroll
            for (int ks = 0; ks < 4; ++ks)
                acc = __builtin_amdgcn_mfma_f32_16x16x32_bf16(jh[ks], ihi[ks], acc, 0, 0, 0);
#pragma unroll
            for (int ks = 0; ks < 4; ++ks)
                acc = __builtin_amdgcn_mfma_f32_16x16x32_bf16(jl[ks], ihi[ks], acc, 0, 0, 0);
#pragma unroll
            for (int ks = 0; ks < 4; ++ks)
                acc = __builtin_amdgcn_mfma_f32_16x16x32_bf16(jh[ks], ilo[ks], acc, 0, 0, 0);

            // ---- epilogue: 4 consecutive j for this lane's single i ----
            const int j0 = j0base + 16 * jf;
            const float4 sq4 = *reinterpret_cast<const float4*>(&sq[j0 < NN - 4 ? j0 : NN - 4]);
            const float* sqp = reinterpret_cast<const float*>(&sq4);
            const float* qp = reinterpret_cast<const float*>(&qv[jf]);
#pragma unroll
            for (int r = 0; r < 4; ++r) {
                int j = j0 + r;
                float d2 = fmaxf(fmaf(-2.f, acc[r], sqi + sqp[r]), 0.f);
                float u = -fast_ln(qp[r] + 1e-8f);         // relative-accurate near q~1
                float g = __log2f(u) * NLN2;               // -ln(u); abs err ~1e-7 ok
                float v = (j < jlimit) ? fmaf(-T, d2, g) : NEG_INF;
                if (v > tv[3]) {
                    tv[3] = v; tj[3] = j;
#pragma unroll
                    for (int rr = 3; rr > 0; --rr) {
                        if (BETTER(tv[rr], tj[rr], tv[rr - 1], tj[rr - 1])) {
                            float t0 = tv[rr]; tv[rr] = tv[rr - 1]; tv[rr - 1] = t0;
                            int t1 = tj[rr]; tj[rr] = tj[rr - 1]; tj[rr - 1] = t1;
                        }
                    }
                }
            }
        }
    }

    // ---- in-block merge: 4 kl-lanes per i-row ----
    __syncthreads();
    float* mv = reinterpret_cast<float*>(Bhi);  // 64 rows x 16 entries
    int* mj = reinterpret_cast<int*>(Blo);
    {
        int rl = 16 * w + n;
#pragma unroll
        for (int s = 0; s < 4; ++s) {
            mv[rl * 16 + kl * 4 + s] = tv[s];
            mj[rl * 16 + kl * 4 + s] = tj[s];
        }
    }
    __syncthreads();
    if (tid < 64) {
        int i = ibase + tid;
        float bv[4] = {NEG_INF, NEG_INF, NEG_INF, NEG_INF};
        int bj[4] = {0x7fffffff, 0x7fffffff, 0x7fffffff, 0x7fffffff};
        for (int c = 0; c < 16; ++c) {
            float v = mv[tid * 16 + c];
            int j = mj[tid * 16 + c];
            INSERT4(bv, bj, v, j)
        }
        if (i < NN) {
#pragma unroll
            for (int s = 0; s < 4; ++s) {
                pvals[(split * NN + i) * 4 + s] = bv[s];
                pidx[(split * NN + i) * 4 + s] = bj[s];
            }
        }
    }
}

// -------------------- final cross-split merge + output assembly --------------------
__global__ void k_merge(const float* __restrict__ pvals, const int* __restrict__ pidx,
                        float* __restrict__ out) {
    int i = blockIdx.x * blockDim.x + threadIdx.x;
    if (i >= NN) return;
    float mv[4] = {NEG_INF, NEG_INF, NEG_INF, NEG_INF};
    int mj[4] = {0x7fffffff, 0x7fffffff, 0x7fffffff, 0x7fffffff};
    for (int s = 0; s < JSPLIT; ++s) {
#pragma unroll
        for (int r = 0; r < 4; ++r) {
            float v = pvals[(s * NN + i) * 4 + r];
            int j = pidx[(s * NN + i) * 4 + r];
            INSERT4(mv, mj, v, j)
        }
    }
    float* eidx = out + NN * DD;
    float* erow = eidx + (NN * KT + NN);
    float* lp = erow + (NN * KT + NN);
#pragma unroll
    for (int r = 0; r < 4; ++r) {
        eidx[i * 4 + r] = (float)mj[r];
        erow[i * 4 + r] = (float)i;
        lp[i * 4 + r] = mv[r];
    }
    eidx[NN * KT + i] = (float)i;
    erow[NN * KT + i] = (float)i;
}

extern "C" void kernel_launch(void* const* d_in, const int* in_sizes, int n_in,
                              void* d_out, int out_size, void* d_ws, size_t ws_size,
                              hipStream_t stream) {
    const float* x = (const float*)d_in[0];
    const int* ei = (const int*)d_in[1];
    const float* q = (const float*)d_in[2];
    const float* W = (const float*)d_in[3];
    const float* b = (const float*)d_in[4];
    const float* temp = (const float*)d_in[5];
    float* out = (float*)d_out;

    char* ws = (char*)d_ws;
    float* hpre = (float*)(ws + 0);                          // 5,120,000
    unsigned short* hhi = (unsigned short*)(ws + 5120000);   // 2,588,672 -> 7,708,672
    unsigned short* hlo = (unsigned short*)(ws + 7708672);   // 2,588,672 -> 10,297,344
    float* pvals = (float*)(ws + 10297344);                  // 2,560,000 -> 12,857,344
    int* pidx = (int*)(ws + 12857344);                       // 2,560,000 -> 15,417,344
    float* sq = (float*)(ws + 15417344);                     // 40,448 -> 15,457,792
    int* cnt = (int*)(ws + 15457792);                        // 40,000 -> 15,497,792 (also wcnt)
    int* rowptr = (int*)(ws + 15497792);                     // 40,016 -> 15,537,808
    float* dinv = (float*)(ws + 15537808);                   // 40,000 -> 15,577,808
    int* csr = (int*)(ws + 15577808);                        // 640,000 -> 16,217,808

    // zero edge-count histogram each launch (ws poisoned once, never restored)
    hipMemsetAsync(cnt, 0, 40000, stream);

    k_gemm<<<313, 256, 0, stream>>>(x, W, hpre);
    k_count<<<(EE + 255) / 256, 256, 0, stream>>>(ei, cnt);
    k_scan<<<1, 1024, 0, stream>>>(cnt, rowptr, dinv);
    k_fill<<<(EE + 255) / 256, 256, 0, stream>>>(ei, rowptr, cnt, csr);
    k_gather<<<NPAD, 128, 0, stream>>>(hpre, rowptr, csr, dinv, b, out, hhi, hlo, sq);
    k_topk<<<ITILES * JSPLIT, 256, 0, stream>>>(hhi, hlo, sq, q, temp, pvals, pidx);
    k_merge<<<(NN + 255) / 256, 256, 0, stream>>>(pvals, pidx, out);
}

// Round 7
// 357.022 us; speedup vs baseline: 1.7647x; 1.5785x over previous
//
#include <hip/hip_runtime.h>

#define NN 10000
#define NPAD 10112
#define EE 160000
#define DD 128
#define KT 4

constexpr int JSPLIT = 16;
constexpr int ITILES = 157;                 // ceil(10000/64), BM=64
constexpr int JCHUNK = 628;                 // multiple of 4 -> 16B-aligned q float4 loads
constexpr double FPSCALE = 1099511627776.0; // 2^40
constexpr float NEG_INF = -3.402823466e38f;
constexpr float NLN2 = -0.69314718055994531f;

// LDS j-tile layout: 64 rows x 136 shorts (272 B stride = 17 chunks of 16 B).
// The +16B pad rotates bank groups by (row mod 8) -> same conflict profile as the
// old XOR swizzle, but every read/write address = one per-lane base + IMMEDIATE.
constexpr int RSTRIDE_B = 272;              // bytes per row
constexpr int LO_OFF = 64 * RSTRIDE_B;      // 17408 B: lo-plane offset inside Bsh

typedef __attribute__((ext_vector_type(8))) short short8;
typedef __attribute__((ext_vector_type(8))) unsigned short ushort8;
typedef __attribute__((ext_vector_type(4))) float f32x4;

// -------------------- bf16 split helpers --------------------
__device__ inline unsigned short bf_rn(float x) {
    unsigned u = __float_as_uint(x);
    unsigned r = (u + 0x7fffu + ((u >> 16) & 1u)) >> 16;
    return (unsigned short)r;
}
__device__ inline float bf_f(unsigned short h) {
    return __uint_as_float(((unsigned)h) << 16);
}

// -------------------- h0 = x @ W, LDS-tiled (32 rows/block) --------------------
__global__ __launch_bounds__(256) void k_gemm(const float* __restrict__ x,
                                              const float* __restrict__ W,
                                              float* __restrict__ hpre) {
    __shared__ float4 Ws4[128 * 32];   // [k][c4]  64 KB
    __shared__ float4 xs4[32 * 32];    // [row][k4] 16 KB
    const int t = threadIdx.x;
    const int r0 = blockIdx.x * 32;
    const float4* W4 = reinterpret_cast<const float4*>(W);
    const float4* x4 = reinterpret_cast<const float4*>(x);
#pragma unroll
    for (int i = 0; i < 16; ++i) Ws4[i * 256 + t] = W4[i * 256 + t];
#pragma unroll
    for (int i = 0; i < 4; ++i) {
        int f = i * 256 + t;
        int g = r0 * 32 + f;
        xs4[f] = (g < NN * 32) ? x4[g] : make_float4(0.f, 0.f, 0.f, 0.f);
    }
    __syncthreads();
    const int c = t & 31;    // float4 column
    const int rg = t >> 5;   // 0..7 -> rows rg*4..rg*4+3
    float4 acc[4] = {};
    for (int k4 = 0; k4 < 32; ++k4) {
        float4 w0 = Ws4[(k4 * 4 + 0) * 32 + c];
        float4 w1 = Ws4[(k4 * 4 + 1) * 32 + c];
        float4 w2 = Ws4[(k4 * 4 + 2) * 32 + c];
        float4 w3 = Ws4[(k4 * 4 + 3) * 32 + c];
#pragma unroll
        for (int r = 0; r < 4; ++r) {
            float4 xv = xs4[(rg * 4 + r) * 32 + k4];
            acc[r].x = fmaf(xv.w, w3.x, fmaf(xv.z, w2.x, fmaf(xv.y, w1.x, fmaf(xv.x, w0.x, acc[r].x))));
            acc[r].y = fmaf(xv.w, w3.y, fmaf(xv.z, w2.y, fmaf(xv.y, w1.y, fmaf(xv.x, w0.y, acc[r].y))));
            acc[r].z = fmaf(xv.w, w3.z, fmaf(xv.z, w2.z, fmaf(xv.y, w1.z, fmaf(xv.x, w0.z, acc[r].z))));
            acc[r].w = fmaf(xv.w, w3.w, fmaf(xv.z, w2.w, fmaf(xv.y, w1.w, fmaf(xv.x, w0.w, acc[r].w))));
        }
    }
#pragma unroll
    for (int r = 0; r < 4; ++r) {
        int row = r0 + rg * 4 + r;
        if (row < NN) reinterpret_cast<float4*>(hpre)[row * 32 + c] = acc[r];
    }
}

// -------------------- CSR build: count -> scan(+dinv) -> fill --------------------
__global__ void k_count(const int* __restrict__ ei, int* __restrict__ cnt) {
    int e = blockIdx.x * blockDim.x + threadIdx.x;
    if (e < EE) atomicAdd(&cnt[ei[e]], 1);
}

__global__ void k_scan(int* __restrict__ cnt, int* __restrict__ rowptr,
                       float* __restrict__ dinv) {
    __shared__ int part[1024];
    int t = threadIdx.x;
    int base = t * 10;
    int loc[10];
    int s = 0;
#pragma unroll
    for (int k = 0; k < 10; ++k) {
        int idx = base + k;
        int v = (idx < NN) ? cnt[idx] : 0;
        loc[k] = s; s += v;
    }
    part[t] = s;
    __syncthreads();
    for (int off = 1; off < 1024; off <<= 1) {
        int v = (t >= off) ? part[t - off] : 0;
        __syncthreads();
        part[t] += v;
        __syncthreads();
    }
    int pre = (t > 0) ? part[t - 1] : 0;
#pragma unroll
    for (int k = 0; k < 10; ++k) {
        int idx = base + k;
        if (idx < NN) {
            rowptr[idx] = pre + loc[k];
            int d = cnt[idx];
            dinv[idx] = 1.0f / sqrtf((float)(d + 1));  // + self loop
            cnt[idx] = 0;  // reset for fill phase
        }
    }
    if (t == 1023) rowptr[NN] = part[1023];
}

__global__ void k_fill(const int* __restrict__ ei, const int* __restrict__ rowptr,
                       int* __restrict__ wcnt, int* __restrict__ csr) {
    int e = blockIdx.x * blockDim.x + threadIdx.x;
    if (e >= EE) return;
    int r = ei[e];
    int pos = atomicAdd(&wcnt[r], 1);
    csr[rowptr[r] + pos] = ei[EE + e];
}

// ---------- deterministic gather + fused bf16-split/row-norm ----------
__global__ void k_gather(const float* __restrict__ hpre, const int* __restrict__ rowptr,
                         const int* __restrict__ csr, const float* __restrict__ dinv,
                         const float* __restrict__ b, float* __restrict__ out,
                         unsigned short* __restrict__ hhi, unsigned short* __restrict__ hlo,
                         float* __restrict__ sqout) {
    int r = blockIdx.x;   // NPAD
    int t = threadIdx.x;  // 128
    __shared__ float part[2];
    float outv = 0.f;
    if (r < NN) {
        float dr = dinv[r];
        float v0 = hpre[r * DD + t] * dr * dr;
        long long acc = llrint((double)v0 * FPSCALE);
        int s = rowptr[r], e = rowptr[r + 1];
        for (int k = s; k < e; ++k) {
            int c = csr[k];
            float w = dr * dinv[c];
            float p = hpre[c * DD + t] * w;
            acc += llrint((double)p * FPSCALE);
        }
        outv = (float)((double)acc * (1.0 / FPSCALE)) + b[t];
        out[r * DD + t] = outv;
    }
    unsigned short h0 = bf_rn(outv);
    float rs = outv - bf_f(h0);
    unsigned short l0 = bf_rn(rs);
    hhi[r * DD + t] = h0;
    hlo[r * DD + t] = l0;
    float s2 = outv * outv;
#pragma unroll
    for (int off = 32; off; off >>= 1) s2 += __shfl_xor(s2, off, 64);
    if ((t & 63) == 0) part[t >> 6] = s2;
    __syncthreads();
    if (t == 0) sqout[r] = part[0] + part[1];
}

#define BETTER(v1, j1, v2, j2) ((v1) > (v2) || ((v1) == (v2) && (j1) < (j2)))

#define INSERT4(tvv, tjj, v, j)                                               \
    if (BETTER(v, j, tvv[3], tjj[3])) {                                       \
        tvv[3] = v; tjj[3] = j;                                               \
        _Pragma("unroll")                                                     \
        for (int rr = 3; rr > 0; --rr) {                                      \
            if (BETTER(tvv[rr], tjj[rr], tvv[rr - 1], tjj[rr - 1])) {         \
                float t0 = tvv[rr]; tvv[rr] = tvv[rr - 1]; tvv[rr - 1] = t0;  \
                int t1 = tjj[rr]; tjj[rr] = tjj[rr - 1]; tjj[rr - 1] = t1;    \
            }                                                                 \
        }                                                                     \
    }

// -------------------- MFMA pairwise-dist + gumbel + top-4 (BM=64) --------------------
// D = mfma(A=j-rows(LDS), B=i-rows(regs)): D col = i (lane&15), D row = j (kl*4+r).
// Padded-stride LDS (272 B/row): all tile reads/writes = per-lane base + immediate.
__global__ __launch_bounds__(256, 4) void k_topk(
    const unsigned short* __restrict__ hhi, const unsigned short* __restrict__ hlo,
    const float* __restrict__ sq, const float* __restrict__ q,
    const float* __restrict__ tptr, float* __restrict__ pvals, int* __restrict__ pidx) {
    __shared__ __align__(16) unsigned short Bsh[2 * 64 * 136];  // 34816 B (hi | lo)
    __shared__ __align__(16) float sqs[64];

    const int blk = blockIdx.x;
    const int itile = blk >> 4;
    const int split = blk & 15;
    const int ibase = itile * 64;
    const int jstart = split * JCHUNK;
    const int jlimit = min(NN, jstart + JCHUNK);
    const float T = *tptr;

    const int tid = threadIdx.x;
    const int w = tid >> 6;
    const int lane = tid & 63;
    const int n = lane & 15;     // i-col within wave strip / A(j) row within 16-group
    const int kl = lane >> 4;    // k-slice group; D row group
    const int kl4 = kl * 4;

    // ---- i-side register fragments (B operand): row ibase+16w+n ----
    short8 ihi[4], ilo[4];
    {
        int ra = ibase + 16 * w + n;        // <= 10047 < NPAD
        const unsigned short* pa = hhi + ra * DD + kl * 8;
        const unsigned short* pl = hlo + ra * DD + kl * 8;
#pragma unroll
        for (int ks = 0; ks < 4; ++ks) {
            ihi[ks] = *reinterpret_cast<const short8*>(pa + ks * 32);
            ilo[ks] = *reinterpret_cast<const short8*>(pl + ks * 32);
        }
    }

    const int i_glob = ibase + 16 * w + n;
    const int ic = min(i_glob, NN - 1);
    const float sqi = sq[ic];
    const float* qrow = q + (size_t)ic * NN;

    // per-lane LDS bases (all tile-loop-invariant)
    char* wp = (char*)Bsh + (tid >> 4) * RSTRIDE_B + (tid & 15) * 16;   // staging write
    const char* rp = (const char*)Bsh + n * RSTRIDE_B + kl * 16;        // fragment read
    const char* sp = (const char*)sqs + kl * 16;                        // sq read

    float tv[4];
    int tj[4];
#pragma unroll
    for (int s = 0; s < 4; ++s) { tv[s] = NEG_INF; tj[s] = 0x7fffffff; }

    for (int jt = 0; jt < 10; ++jt) {
        const int jbase = jstart + jt * 64;
        __syncthreads();  // previous-tile LDS reads done
        // ---- stage j-tile (hi+lo): immediate-offset writes ----
        {
            const unsigned short* gh = hhi + (size_t)(jbase + (tid >> 4)) * DD + (tid & 15) * 8;
            const unsigned short* gl = hlo + (size_t)(jbase + (tid >> 4)) * DD + (tid & 15) * 8;
#pragma unroll
            for (int p = 0; p < 4; ++p) {   // p*16 rows -> +p*16*272 B; +p*2048 elems global
                *reinterpret_cast<ushort8*>(wp + p * (16 * RSTRIDE_B)) =
                    *reinterpret_cast<const ushort8*>(gh + p * 2048);
                *reinterpret_cast<ushort8*>(wp + LO_OFF + p * (16 * RSTRIDE_B)) =
                    *reinterpret_cast<const ushort8*>(gl + p * 2048);
            }
        }
        if (tid < 64) sqs[tid] = sq[jbase + tid];
        __syncthreads();

        // ---- q prefetch: one float4 per jf; immediate offsets except final clamp tile ----
        float4 qv[4];
        if (jbase <= NN - 64) {
            const float* qt = qrow + (jbase + kl4);
#pragma unroll
            for (int jf = 0; jf < 4; ++jf)
                qv[jf] = *reinterpret_cast<const float4*>(qt + 16 * jf);
        } else {   // only split 15, jt 9: clamp to stay inside q
#pragma unroll
            for (int jf = 0; jf < 4; ++jf) {
                int j0 = jbase + 16 * jf + kl4;
                int jq = min(j0, NN - 4);
                qv[jf] = *reinterpret_cast<const float4*>(qrow + jq);
            }
        }

#pragma unroll
        for (int jf = 0; jf < 4; ++jf) {
            short8 jh[4], jl[4];
#pragma unroll
            for (int ks = 0; ks < 4; ++ks) {   // base + jf*4352 + ks*64 (+LO_OFF)
                jh[ks] = *reinterpret_cast<const short8*>(rp + jf * (16 * RSTRIDE_B) + ks * 64);
                jl[ks] = *reinterpret_cast<const short8*>(rp + LO_OFF + jf * (16 * RSTRIDE_B) + ks * 64);
            }
            f32x4 acc = {0.f, 0.f, 0.f, 0.f};
#pragma unroll
            for (int ks = 0; ks < 4; ++ks)
                acc = __builtin_amdgcn_mfma_f32_16x16x32_bf16(jh[ks], ihi[ks], acc, 0, 0, 0);
#pragma unroll
            for (int ks = 0; ks < 4; ++ks)
                acc = __builtin_amdgcn_mfma_f32_16x16x32_bf16(jl[ks], ihi[ks], acc, 0, 0, 0);
#pragma unroll
            for (int ks = 0; ks < 4; ++ks)
                acc = __builtin_amdgcn_mfma_f32_16x16x32_bf16(jh[ks], ilo[ks], acc, 0, 0, 0);

            // ---- epilogue: 4 consecutive j for this lane's single i ----
            const float4 sq4 = *reinterpret_cast<const float4*>(sp + jf * 64);
            const int j0 = jbase + 16 * jf + kl4;
            const float* sqp = reinterpret_cast<const float*>(&sq4);
            const float* qp = reinterpret_cast<const float*>(&qv[jf]);
#pragma unroll
            for (int r = 0; r < 4; ++r) {
                float d2 = fmaxf(fmaf(-2.f, acc[r], sqi + sqp[r]), 0.f);
                float qe = qp[r] + 1e-8f;
                // u = -ln(qe): atanh-poly (rel err ~1.6e-6) for qe>=0.5 (Sterbenz zone),
                // hardware log2 (rel err ~1e-7 there) for qe<0.5.
                float t  = (qe - 1.f) * __builtin_amdgcn_rcpf(qe + 1.f);
                float t2 = t * t;
                float pp = fmaf(0.11111111f, t2, 0.14285714f);
                pp = fmaf(pp, t2, 0.2f);
                pp = fmaf(pp, t2, 0.33333333f);
                pp = fmaf(pp, t2, 1.f);
                float udir = (-2.f * t) * pp;
                float ulog = __log2f(qe) * NLN2;
                float u = (qe >= 0.5f) ? udir : ulog;
                float g = __log2f(u) * NLN2;               // -ln(u); abs err ~1e-7 ok
                float v = (j0 + r < jlimit) ? fmaf(-T, d2, g) : NEG_INF;
                // strict gate: per-lane j ascends, so equal-v later-j correctly rejected
                if (v > tv[3]) {
                    int j = j0 + r;
                    tv[3] = v; tj[3] = j;
#pragma unroll
                    for (int rr = 3; rr > 0; --rr) {
                        if (BETTER(tv[rr], tj[rr], tv[rr - 1], tj[rr - 1])) {
                            float t0 = tv[rr]; tv[rr] = tv[rr - 1]; tv[rr - 1] = t0;
                            int t1 = tj[rr]; tj[rr] = tj[rr - 1]; tj[rr - 1] = t1;
                        }
                    }
                }
            }
        }
    }

    // ---- in-block merge: 4 kl-lanes per i-row ----
    __syncthreads();
    float* mv = reinterpret_cast<float*>(Bsh);                    // 64 rows x 16
    int* mj = reinterpret_cast<int*>((char*)Bsh + LO_OFF);
    {
        int rl = 16 * w + n;
#pragma unroll
        for (int s = 0; s < 4; ++s) {
            mv[rl * 16 + kl4 + s] = tv[s];
            mj[rl * 16 + kl4 + s] = tj[s];
        }
    }
    __syncthreads();
    if (tid < 64) {
        int i = ibase + tid;
        float bv[4] = {NEG_INF, NEG_INF, NEG_INF, NEG_INF};
        int bj[4] = {0x7fffffff, 0x7fffffff, 0x7fffffff, 0x7fffffff};
        for (int c = 0; c < 16; ++c) {
            float v = mv[tid * 16 + c];
            int j = mj[tid * 16 + c];
            INSERT4(bv, bj, v, j)
        }
        if (i < NN) {
#pragma unroll
            for (int s = 0; s < 4; ++s) {
                pvals[(split * NN + i) * 4 + s] = bv[s];
                pidx[(split * NN + i) * 4 + s] = bj[s];
            }
        }
    }
}

// -------------------- final cross-split merge + output assembly --------------------
__global__ void k_merge(const float* __restrict__ pvals, const int* __restrict__ pidx,
                        float* __restrict__ out) {
    int i = blockIdx.x * blockDim.x + threadIdx.x;
    if (i >= NN) return;
    float mv[4] = {NEG_INF, NEG_INF, NEG_INF, NEG_INF};
    int mj[4] = {0x7fffffff, 0x7fffffff, 0x7fffffff, 0x7fffffff};
    for (int s = 0; s < JSPLIT; ++s) {
#pragma unroll
        for (int r = 0; r < 4; ++r) {
            float v = pvals[(s * NN + i) * 4 + r];
            int j = pidx[(s * NN + i) * 4 + r];
            INSERT4(mv, mj, v, j)
        }
    }
    float* eidx = out + NN * DD;
    float* erow = eidx + (NN * KT + NN);
    float* lp = erow + (NN * KT + NN);
#pragma unroll
    for (int r = 0; r < 4; ++r) {
        eidx[i * 4 + r] = (float)mj[r];
        erow[i * 4 + r] = (float)i;
        lp[i * 4 + r] = mv[r];
    }
    eidx[NN * KT + i] = (float)i;
    erow[NN * KT + i] = (float)i;
}

extern "C" void kernel_launch(void* const* d_in, const int* in_sizes, int n_in,
                              void* d_out, int out_size, void* d_ws, size_t ws_size,
                              hipStream_t stream) {
    const float* x = (const float*)d_in[0];
    const int* ei = (const int*)d_in[1];
    const float* q = (const float*)d_in[2];
    const float* W = (const float*)d_in[3];
    const float* b = (const float*)d_in[4];
    const float* temp = (const float*)d_in[5];
    float* out = (float*)d_out;

    char* ws = (char*)d_ws;
    float* hpre = (float*)(ws + 0);                          // 5,120,000
    unsigned short* hhi = (unsigned short*)(ws + 5120000);   // 2,588,672 -> 7,708,672
    unsigned short* hlo = (unsigned short*)(ws + 7708672);   // 2,588,672 -> 10,297,344
    float* pvals = (float*)(ws + 10297344);                  // 2,560,000 -> 12,857,344
    int* pidx = (int*)(ws + 12857344);                       // 2,560,000 -> 15,417,344
    float* sq = (float*)(ws + 15417344);                     // 40,448 -> 15,457,792
    int* cnt = (int*)(ws + 15457792);                        // 40,000 -> 15,497,792 (also wcnt)
    int* rowptr = (int*)(ws + 15497792);                     // 40,016 -> 15,537,808
    float* dinv = (float*)(ws + 15537808);                   // 40,000 -> 15,577,808
    int* csr = (int*)(ws + 15577808);                        // 640,000 -> 16,217,808

    // zero edge-count histogram each launch (ws poisoned once, never restored)
    hipMemsetAsync(cnt, 0, 40000, stream);

    k_gemm<<<313, 256, 0, stream>>>(x, W, hpre);
    k_count<<<(EE + 255) / 256, 256, 0, stream>>>(ei, cnt);
    k_scan<<<1, 1024, 0, stream>>>(cnt, rowptr, dinv);
    k_fill<<<(EE + 255) / 256, 256, 0, stream>>>(ei, rowptr, cnt, csr);
    k_gather<<<NPAD, 128, 0, stream>>>(hpre, rowptr, csr, dinv, b, out, hhi, hlo, sq);
    k_topk<<<ITILES * JSPLIT, 256, 0, stream>>>(hhi, hlo, sq, q, temp, pvals, pidx);
    k_merge<<<(NN + 255) / 256, 256, 0, stream>>>(pvals, pidx, out);
}